// Round 1
// baseline (153.395 us; speedup 1.0000x reference)
//
#include <hip/hip_runtime.h>
#include <hip/hip_bf16.h>

// z: (8,2048,64) f32 -> N=16384, D=64 ; codebook: (8192,64) f32
// outputs (f32, concat): z_q_st[1048576], vq_loss[1], idx[16384],
//   new_codebook[524288], new_cs[8192], new_ws[524288]
//
// Distance argmin via f16-split MFMA: x = xh + xl. dot(x,c) ~= Xh.Ch + Xh.Cl
// + Xl.Ch. argmin ||x-c||^2 == argmax (dot - 0.5||c||^2); -0.5||c||^2 is
// folded into the MFMA accumulator init. The f16-split codebook is
// precomputed ONCE (k_prep) into a swizzled image whose group blocks are
// byte-identical to the LDS layout -> k_mfma stages via global_load_lds DMA.
//
// R1: k_mfma restructured to double-buffered LDS staging (2 x 32 KB) with
// counted s_waitcnt vmcnt(8) + raw s_barrier (T3+T4) and s_setprio around
// the compute phase (T5). Removes the per-group vmcnt(0) barrier drain.

#define NQ 16384
#define KC 8192
#define DD 64
#define NSPLIT 8
#define CSPLIT (KC / NSPLIT)     // 1024 codes per block job
#define GROUP 128                // codes staged in LDS per barrier
#define NGROUP (CSPLIT / GROUP)  // 8
#define NTILE (GROUP / 16)       // 8 MFMA c-tiles per staged group
#define IMGH 16384               // halves per group image (32 KB)

#define SC_BLOCKS 256
#define SC_CODES (KC / SC_BLOCKS)  // 32 codes per tail block

typedef _Float16 half8 __attribute__((ext_vector_type(8)));
typedef _Float16 half4v __attribute__((ext_vector_type(4)));
typedef float f32x4 __attribute__((ext_vector_type(4)));
typedef unsigned int u32;

__device__ __forceinline__ void async_copy16(const _Float16* g, _Float16* l) {
  __builtin_amdgcn_global_load_lds(
      (const __attribute__((address_space(1))) u32*)(const void*)g,
      (__attribute__((address_space(3))) u32*)(void*)l, 16, 0, 0);
}

// ---------------- workspace layout (floats) ----------------
// [0)       nhcn    8192    (-0.5*||c||^2)
// [8192)    epart   32      (ema_cs partial sums, non-atomic)
// [8256)    parts   4096    (loss partials, one per k_assign block)
// [12352)   pmax    131072  (8 x 16384 partial max-u)
// [143424)  pidx    131072  (int)
// [274496)  idx_i   16384   (int)
// [290880)  Cxs     524288  (f16 x 1048576: 64 group images x 32 KB)

// k_prep: swizzled f16-split codebook image + nhcn + ema partials.
// thread = (code c, j4) ; c = gid>>4, j4 = gid&15 covers f32x4 d=4*j4..
__global__ __launch_bounds__(256) void k_prep(
    const float* __restrict__ cb, const float* __restrict__ ema_cs,
    _Float16* __restrict__ Cxs, float* __restrict__ nhcn,
    float* __restrict__ epart) {
  const int t = threadIdx.x;
  const int gid = blockIdx.x * 256 + t;
  const int c = gid >> 4;
  const int j4 = gid & 15;

  const f32x4 v = ((const f32x4*)cb)[gid];
  half4v hh, ll;
  float s = 0.f;
#pragma unroll
  for (int e = 0; e < 4; ++e) {
    const float f = v[e];
    const _Float16 h = (_Float16)f;
    hh[e] = h;
    ll[e] = (_Float16)(f - (float)h);
    s = fmaf(f, f, s);
  }
  // swizzled slot (identical formula to the R9/R10 in-kernel staging)
  const int r = c & 127;           // row in group
  const int tt = r >> 4;
  const int n = r & 15;
  const int q = (j4 >> 1) & 3;
  const int ihalf = j4 & 1;
  const int frh = j4 >> 3;
  const int fs = frh * 4 + q;
  const int nw = n ^ fs;
  _Float16* img = Cxs + (size_t)(c >> 7) * IMGH;
  *(half4v*)(img + ((size_t)((tt * 4 + frh) * 64 + q * 16 + nw)) * 8 +
             ihalf * 4) = hh;
  *(half4v*)(img + ((size_t)((tt * 4 + frh + 2) * 64 + q * 16 + nw)) * 8 +
             ihalf * 4) = ll;

  // row sumsq: reduce across the 16 lanes of this row (lanes j4=0..15)
#pragma unroll
  for (int off = 1; off < 16; off <<= 1) s += __shfl_xor(s, off, 64);
  if (j4 == 0) nhcn[c] = -0.5f * s;

  // ema partials: blocks 0..31 each reduce 256 values (non-atomic write)
  if (blockIdx.x < 32) {
    float su = ema_cs[blockIdx.x * 256 + t];
#pragma unroll
    for (int off = 1; off < 64; off <<= 1) su += __shfl_xor(su, off, 64);
    __shared__ float ss[4];
    if ((t & 63) == 0) ss[t >> 6] = su;
    __syncthreads();
    if (t == 0) epart[blockIdx.x] = ss[0] + ss[1] + ss[2] + ss[3];
  }
}

// MFMA argmax. Wave = 32 queries (2 16x16 q-tiles), block job = 1024 codes.
// Staging = double-buffered linear global_load_lds DMA of the precomputed
// group image; counted vmcnt(8) keeps the next group's loads in flight
// across the barrier (no drain-to-0 in the steady state).
// acc init = -0.5||c||^2 -> u = acc[r] directly after the 6 MFMAs.
__global__ __launch_bounds__(256, 2) void k_mfma(
    const float* __restrict__ z, const _Float16* __restrict__ Cxs,
    const float* __restrict__ nhcn, float* __restrict__ pmax,
    int* __restrict__ pidx) {
  __shared__ _Float16 Bs[2 * IMGH];  // 64 KB (double buffer)
  const int t = threadIdx.x;
  const int lane = t & 63;
  const int w = t >> 6;
  const int split = blockIdx.y;
  const int Qw = blockIdx.x * 128 + w * 32;
  const int n16 = lane & 15;
  const int quad = lane >> 4;

  // A-frags: z rows -> f16 split in registers (layout: lane holds
  // A[m=lane&15][k=(lane>>4)*8+j]; frag hf covers k/d in [32*hf, 32*hf+32)).
  const f32x4* __restrict__ z4 = (const f32x4*)z;
  half8 aH0[2], aH1[2], aL0[2], aL1[2];
#pragma unroll
  for (int qt = 0; qt < 2; ++qt) {
    const size_t row16 = (size_t)(Qw + qt * 16 + n16) * 16;
#pragma unroll
    for (int hf = 0; hf < 2; ++hf) {
      const size_t rb = row16 + hf * 8 + quad * 2;
      const f32x4 va = z4[rb];
      const f32x4 vb = z4[rb + 1];
      half8 H, L;
#pragma unroll
      for (int e = 0; e < 4; ++e) {
        const float fa = va[e], fb = vb[e];
        const _Float16 ha = (_Float16)fa, hb = (_Float16)fb;
        H[e] = ha; H[e + 4] = hb;
        L[e] = (_Float16)(fa - (float)ha);
        L[e + 4] = (_Float16)(fb - (float)hb);
      }
      if (hf == 0) { aH0[qt] = H; aL0[qt] = L; }
      else         { aH1[qt] = H; aL1[qt] = L; }
    }
  }

  float best[2][4];
  int bidx[2][4];
#pragma unroll
  for (int qt = 0; qt < 2; ++qt)
#pragma unroll
    for (int r = 0; r < 4; ++r) {
      best[qt][r] = -3.4e38f;
      bidx[qt][r] = 0;
    }

  // prologue: stage group 0 into buffer 0
  {
    const _Float16* gimg = Cxs + (size_t)(split * NGROUP) * IMGH;
#pragma unroll
    for (int p = 0; p < 8; ++p) {
      const int off = (t + 256 * p) * 8;  // halves
      async_copy16(gimg + off, Bs + off);
    }
  }

  for (int g = 0; g < NGROUP; ++g) {
    const int C0 = split * CSPLIT + g * GROUP;
    const _Float16* __restrict__ buf = Bs + (g & 1) * IMGH;

    if (g + 1 < NGROUP) {
      // issue next group's DMA into the other buffer. Safe: the barrier at
      // the end of iteration g-1 guarantees all waves finished reading it.
      const _Float16* gimg = Cxs + (size_t)(split * NGROUP + g + 1) * IMGH;
      _Float16* nbuf = Bs + ((g + 1) & 1) * IMGH;
#pragma unroll
      for (int p = 0; p < 8; ++p) {
        const int off = (t + 256 * p) * 8;
        async_copy16(gimg + off, nbuf + off);
      }
      // oldest-first retire: waits group g's 8 loads (and any straggler
      // nhcn loads), leaves the 8 just-issued in flight.
      asm volatile("s_waitcnt vmcnt(8)" ::: "memory");
    } else {
      asm volatile("s_waitcnt vmcnt(0)" ::: "memory");
    }
    __builtin_amdgcn_s_barrier();
    asm volatile("" ::: "memory");

    const half8* __restrict__ Bs8 = (const half8*)buf;
    __builtin_amdgcn_s_setprio(1);
#pragma unroll
    for (int tt = 0; tt < NTILE; ++tt) {
      const int base = tt * 4 * 64 + quad * 16;
      const half8 b0 = Bs8[base + (n16 ^ quad)];              // Ch k[0,32)
      const half8 b1 = Bs8[base + 64 + (n16 ^ (4 + quad))];   // Ch k[32,64)
      const half8 b2 = Bs8[base + 128 + (n16 ^ quad)];        // Cl k[0,32)
      const half8 b3 = Bs8[base + 192 + (n16 ^ (4 + quad))];  // Cl k[32,64)
      const int c = C0 + tt * 16 + n16;
      const float nc = nhcn[c];
#pragma unroll
      for (int qt = 0; qt < 2; ++qt) {
        f32x4 acc = {nc, nc, nc, nc};
        acc = __builtin_amdgcn_mfma_f32_16x16x32_f16(aH0[qt], b0, acc, 0, 0, 0);
        acc = __builtin_amdgcn_mfma_f32_16x16x32_f16(aH1[qt], b1, acc, 0, 0, 0);
        acc = __builtin_amdgcn_mfma_f32_16x16x32_f16(aH0[qt], b2, acc, 0, 0, 0);
        acc = __builtin_amdgcn_mfma_f32_16x16x32_f16(aH1[qt], b3, acc, 0, 0, 0);
        acc = __builtin_amdgcn_mfma_f32_16x16x32_f16(aL0[qt], b0, acc, 0, 0, 0);
        acc = __builtin_amdgcn_mfma_f32_16x16x32_f16(aL1[qt], b1, acc, 0, 0, 0);
#pragma unroll
        for (int r = 0; r < 4; ++r) {
          const float u = acc[r];
          if (u > best[qt][r]) { best[qt][r] = u; bidx[qt][r] = c; }
        }
      }
    }
    __builtin_amdgcn_s_setprio(0);
    asm volatile("" ::: "memory");
    __builtin_amdgcn_s_barrier();  // all waves done reading buf before it is
                                   // re-targeted by the DMA two iterations on
  }
#pragma unroll
  for (int qt = 0; qt < 2; ++qt)
#pragma unroll
    for (int r = 0; r < 4; ++r) {
      float u = best[qt][r];
      int c = bidx[qt][r];
#pragma unroll
      for (int off = 1; off < 16; off <<= 1) {
        const float u2 = __shfl_xor(u, off, 64);
        const int c2 = __shfl_xor(c, off, 64);
        if (u2 > u || (u2 == u && c2 < c)) { u = u2; c = c2; }
      }
      if (n16 == 0) {
        const int q = Qw + qt * 16 + quad * 4 + r;
        pmax[(size_t)split * NQ + q] = u;
        pidx[(size_t)split * NQ + q] = c;
      }
    }
}

// q-partitioned: merge partial argmax, gather z_q, write idx, loss partial
// (non-atomic, one float per block).
__global__ __launch_bounds__(256) void k_assign(
    const float* __restrict__ z, const float* __restrict__ cb,
    const float* __restrict__ pmax, const int* __restrict__ pidx,
    float* __restrict__ out_zq, float* __restrict__ out_idx,
    int* __restrict__ idx_i, float* __restrict__ parts) {
  const int t = threadIdx.x;
  const int d = t & 63;
  const int w = t >> 6;
  const int q = blockIdx.x * 4 + w;

  const int s = d & 7;
  float v = pmax[(size_t)s * NQ + q];
  int i = pidx[(size_t)s * NQ + q];
#pragma unroll
  for (int off = 1; off < 8; off <<= 1) {
    const float v2 = __shfl_xor(v, off, 64);
    const int i2 = __shfl_xor(i, off, 64);
    if (v2 > v || (v2 == v && i2 < i)) { v = v2; i = i2; }
  }
  const int k = i;  // all lanes agree

  const float zv = z[(size_t)q * DD + d];
  const float cv = cb[(size_t)k * DD + d];
  out_zq[(size_t)q * DD + d] = cv;  // z + (z_q - z)
  const float diff = zv - cv;
  float sq = diff * diff;
#pragma unroll
  for (int off = 1; off < 64; off <<= 1) sq += __shfl_xor(sq, off, 64);
  __shared__ float ss[4];
  if (d == 0) {
    out_idx[q] = (float)k;  // exact in f32 (k < 8192)
    idx_i[q] = k;
    ss[w] = sq;
  }
  __syncthreads();
  if (t == 0) parts[blockIdx.x] = ss[0] + ss[1] + ss[2] + ss[3];
}

// k-partitioned tail: gather dw/cs for 32 owned codes into LDS (ballot scan
// of idx stream), then compute new_cs/new_codebook/new_ws directly. Block 0
// also reduces the loss partials. Zero global atomics anywhere.
__global__ __launch_bounds__(256) void k_tail(
    const float* __restrict__ z, const int* __restrict__ idx_i,
    const float* __restrict__ ema_cs, const float* __restrict__ ema_ws,
    const float* __restrict__ epart, const float* __restrict__ parts,
    float* __restrict__ out_ncs, float* __restrict__ out_ncb,
    float* __restrict__ out_nws, float* __restrict__ out_loss) {
  __shared__ float acc[SC_CODES * 64];  // 8 KB
  __shared__ int cnt[SC_CODES];
  const int t = threadIdx.x;
  const int k0 = blockIdx.x * SC_CODES;
  for (int i = t; i < SC_CODES * 64; i += 256) acc[i] = 0.f;
  if (t < SC_CODES) cnt[t] = 0;
  __syncthreads();

  const int w = t >> 6, lane = t & 63;
  const int qbase = w * (NQ / 4);
#pragma unroll 4
  for (int it = 0; it < NQ / 4 / 64; ++it) {  // 64 iterations
    const int q = qbase + it * 64 + lane;
    const int kv = idx_i[q];
    const bool hit = (unsigned)(kv - k0) < (unsigned)SC_CODES;
    unsigned long long m = __ballot(hit);
    while (m) {
      const int j = __ffsll(m) - 1;
      m &= m - 1;
      const int kj = __shfl(kv, j, 64);
      const int qj = qbase + it * 64 + j;
      const float zvj = z[(size_t)qj * DD + lane];
      atomicAdd(&acc[(kj - k0) * 64 + lane], zvj);
      if (lane == 0) atomicAdd(&cnt[kj - k0], 1);
    }
  }
  __syncthreads();

  // n = 0.99*sum(ema_cs) + 0.01*NQ  (sum(counts) == NQ exactly)
  float esum = 0.f;
#pragma unroll
  for (int b = 0; b < 32; ++b) esum += epart[b];
  const float n = 0.99f * esum + 0.01f * 16384.0f;

  for (int i = t; i < SC_CODES * 64; i += 256) {
    const int kl = i >> 6;
    const int k = k0 + kl;
    const float v = 0.99f * ema_cs[k] + 0.01f * (float)cnt[kl];
    const float smoothed = (v + 1e-5f) / (n + (float)KC * 1e-5f) * n;
    const float nws = 0.99f * ema_ws[(size_t)k * DD + (i & 63)] + 0.01f * acc[i];
    out_nws[(size_t)k0 * DD + i] = nws;
    out_ncb[(size_t)k0 * DD + i] = nws / smoothed;
  }
  if (t < SC_CODES)
    out_ncs[k0 + t] = 0.99f * ema_cs[k0 + t] + 0.01f * (float)cnt[t];

  if (blockIdx.x == 0) {
    __syncthreads();  // acc no longer needed; reuse as reduce scratch
    float s = 0.f;
    for (int i = t; i < 4096; i += 256) s += parts[i];
#pragma unroll
    for (int off = 1; off < 64; off <<= 1) s += __shfl_xor(s, off, 64);
    if ((t & 63) == 0) acc[t >> 6] = s;
    __syncthreads();
    if (t == 0)
      *out_loss = 1.25f * (acc[0] + acc[1] + acc[2] + acc[3]) *
                  (1.0f / 1048576.0f);
  }
}

extern "C" void kernel_launch(void* const* d_in, const int* in_sizes, int n_in,
                              void* d_out, int out_size, void* d_ws,
                              size_t ws_size, hipStream_t stream) {
  const float* z = (const float*)d_in[0];
  const float* cb = (const float*)d_in[1];
  const float* ema_cs = (const float*)d_in[2];
  const float* ema_ws = (const float*)d_in[3];

  float* out = (float*)d_out;
  float* zq_out = out;              // 1048576
  float* loss_out = out + 1048576;  // 1
  float* idx_out = out + 1048577;   // 16384
  float* ncb_out = out + 1064961;   // 524288
  float* ncs_out = out + 1589249;   // 8192
  float* nws_out = out + 1597441;   // 524288

  float* ws = (float*)d_ws;
  float* nhcn = ws;                        // 8192
  float* epart = ws + 8192;                // 32
  float* parts = ws + 8256;                // 4096
  float* pmax = ws + 12352;                // 131072
  int* pidx = (int*)(ws + 143424);         // 131072
  int* idx_i = (int*)(ws + 274496);        // 16384
  _Float16* Cxs = (_Float16*)(ws + 290880);  // 1048576 halves (2 MB)

  k_prep<<<KC * 16 / 256, 256, 0, stream>>>(cb, ema_cs, Cxs, nhcn, epart);
  k_mfma<<<dim3(NQ / 128, NSPLIT), 256, 0, stream>>>(z, Cxs, nhcn, pmax, pidx);
  k_assign<<<NQ / 4, 256, 0, stream>>>(z, cb, pmax, pidx, zq_out, idx_out,
                                       idx_i, parts);
  k_tail<<<SC_BLOCKS, 256, 0, stream>>>(z, idx_i, ema_cs, ema_ws, epart, parts,
                                        ncs_out, ncb_out, nws_out, loss_out);
}

// Round 2
// 149.695 us; speedup vs baseline: 1.0247x; 1.0247x over previous
//
#include <hip/hip_runtime.h>
#include <hip/hip_bf16.h>

// z: (8,2048,64) f32 -> N=16384, D=64 ; codebook: (8192,64) f32
// outputs (f32, concat): z_q_st[1048576], vq_loss[1], idx[16384],
//   new_codebook[524288], new_cs[8192], new_ws[524288]
//
// Distance argmin via f16-split MFMA: x = xh + xl. dot(x,c) ~= Xh.Ch + Xh.Cl
// + Xl.Ch. argmin ||x-c||^2 == argmax (dot - 0.5||c||^2); -0.5||c||^2 is
// folded into the MFMA accumulator init. The f16-split codebook is
// precomputed ONCE (k_prep) into a swizzled image whose group blocks are
// byte-identical to the LDS layout -> k_mfma stages via global_load_lds DMA.
//
// R2: double-buffered staging with GROUP=64 so 2 buffers fit in the original
// 32 KB LDS footprint (R1's 64 KB halved occupancy and regressed). Counted
// s_waitcnt vmcnt(4) + raw s_barrier keeps next group's DMA in flight across
// the barrier. nhcn for the whole split staged once into LDS (4 KB) so the
// K-loop has no VMEM except the staging DMAs (clean vmcnt accounting).
// __launch_bounds__(256,4) restored -> VGPR budget 128, 4 waves/SIMD.

#define NQ 16384
#define KC 8192
#define DD 64
#define NSPLIT 8
#define CSPLIT (KC / NSPLIT)     // 1024 codes per block job
#define GROUP 64                 // codes staged in LDS per barrier
#define NGROUP (CSPLIT / GROUP)  // 16
#define NTILE (GROUP / 16)       // 4 MFMA c-tiles per staged group
#define IMGH 8192                // halves per group image (16 KB)

#define SC_BLOCKS 256
#define SC_CODES (KC / SC_BLOCKS)  // 32 codes per tail block

typedef _Float16 half8 __attribute__((ext_vector_type(8)));
typedef _Float16 half4v __attribute__((ext_vector_type(4)));
typedef float f32x4 __attribute__((ext_vector_type(4)));
typedef unsigned int u32;

__device__ __forceinline__ void async_copy16(const _Float16* g, _Float16* l) {
  __builtin_amdgcn_global_load_lds(
      (const __attribute__((address_space(1))) u32*)(const void*)g,
      (__attribute__((address_space(3))) u32*)(void*)l, 16, 0, 0);
}

// ---------------- workspace layout (floats) ----------------
// [0)       nhcn    8192    (-0.5*||c||^2)
// [8192)    epart   32      (ema_cs partial sums, non-atomic)
// [8256)    parts   4096    (loss partials, one per k_assign block)
// [12352)   pmax    131072  (8 x 16384 partial max-u)
// [143424)  pidx    131072  (int)
// [274496)  idx_i   16384   (int)
// [290880)  Cxs     524288  (f16 x 1048576: 128 group images x 16 KB)

// k_prep: swizzled f16-split codebook image + nhcn + ema partials.
// thread = (code c, j4) ; c = gid>>4, j4 = gid&15 covers f32x4 d=4*j4..
__global__ __launch_bounds__(256) void k_prep(
    const float* __restrict__ cb, const float* __restrict__ ema_cs,
    _Float16* __restrict__ Cxs, float* __restrict__ nhcn,
    float* __restrict__ epart) {
  const int t = threadIdx.x;
  const int gid = blockIdx.x * 256 + t;
  const int c = gid >> 4;
  const int j4 = gid & 15;

  const f32x4 v = ((const f32x4*)cb)[gid];
  half4v hh, ll;
  float s = 0.f;
#pragma unroll
  for (int e = 0; e < 4; ++e) {
    const float f = v[e];
    const _Float16 h = (_Float16)f;
    hh[e] = h;
    ll[e] = (_Float16)(f - (float)h);
    s = fmaf(f, f, s);
  }
  // swizzled slot (same formula as the LDS-consumer in k_mfma)
  const int r = c & (GROUP - 1);   // row in group
  const int tt = r >> 4;
  const int n = r & 15;
  const int q = (j4 >> 1) & 3;
  const int ihalf = j4 & 1;
  const int frh = j4 >> 3;
  const int fs = frh * 4 + q;
  const int nw = n ^ fs;
  _Float16* img = Cxs + (size_t)(c / GROUP) * IMGH;
  *(half4v*)(img + ((size_t)((tt * 4 + frh) * 64 + q * 16 + nw)) * 8 +
             ihalf * 4) = hh;
  *(half4v*)(img + ((size_t)((tt * 4 + frh + 2) * 64 + q * 16 + nw)) * 8 +
             ihalf * 4) = ll;

  // row sumsq: reduce across the 16 lanes of this row (lanes j4=0..15)
#pragma unroll
  for (int off = 1; off < 16; off <<= 1) s += __shfl_xor(s, off, 64);
  if (j4 == 0) nhcn[c] = -0.5f * s;

  // ema partials: blocks 0..31 each reduce 256 values (non-atomic write)
  if (blockIdx.x < 32) {
    float su = ema_cs[blockIdx.x * 256 + t];
#pragma unroll
    for (int off = 1; off < 64; off <<= 1) su += __shfl_xor(su, off, 64);
    __shared__ float ss[4];
    if ((t & 63) == 0) ss[t >> 6] = su;
    __syncthreads();
    if (t == 0) epart[blockIdx.x] = ss[0] + ss[1] + ss[2] + ss[3];
  }
}

// MFMA argmax. Wave = 32 queries (2 16x16 q-tiles), block job = 1024 codes.
// Double-buffered global_load_lds staging of 16 KB group images; counted
// vmcnt(4) keeps the next group's loads in flight across the barrier.
// nhcn staged once to LDS -> no VMEM in the K-loop besides the DMAs.
__global__ __launch_bounds__(256, 4) void k_mfma(
    const float* __restrict__ z, const _Float16* __restrict__ Cxs,
    const float* __restrict__ nhcn, float* __restrict__ pmax,
    int* __restrict__ pidx) {
  __shared__ _Float16 Bs[2 * IMGH];  // 32 KB (double buffer)
  __shared__ float nh[CSPLIT];       // 4 KB
  const int t = threadIdx.x;
  const int lane = t & 63;
  const int w = t >> 6;
  const int split = blockIdx.y;
  const int Qw = blockIdx.x * 128 + w * 32;
  const int n16 = lane & 15;
  const int quad = lane >> 4;

  // nhcn for this split -> LDS (one f32x4 per thread)
  const f32x4 nhv = ((const f32x4*)(nhcn + split * CSPLIT))[t];

  // prologue: stage group 0 into buffer 0
  {
    const _Float16* gimg = Cxs + (size_t)(split * NGROUP) * IMGH;
#pragma unroll
    for (int p = 0; p < 4; ++p) {
      const int off = (t + 256 * p) * 8;  // halves
      async_copy16(gimg + off, Bs + off);
    }
  }
  ((f32x4*)nh)[t] = nhv;

  // A-frags: z rows -> f16 split in registers (layout: lane holds
  // A[m=lane&15][k=(lane>>4)*8+j]; frag hf covers k/d in [32*hf, 32*hf+32)).
  const f32x4* __restrict__ z4 = (const f32x4*)z;
  half8 aH0[2], aH1[2], aL0[2], aL1[2];
#pragma unroll
  for (int qt = 0; qt < 2; ++qt) {
    const size_t row16 = (size_t)(Qw + qt * 16 + n16) * 16;
#pragma unroll
    for (int hf = 0; hf < 2; ++hf) {
      const size_t rb = row16 + hf * 8 + quad * 2;
      const f32x4 va = z4[rb];
      const f32x4 vb = z4[rb + 1];
      half8 H, L;
#pragma unroll
      for (int e = 0; e < 4; ++e) {
        const float fa = va[e], fb = vb[e];
        const _Float16 ha = (_Float16)fa, hb = (_Float16)fb;
        H[e] = ha; H[e + 4] = hb;
        L[e] = (_Float16)(fa - (float)ha);
        L[e + 4] = (_Float16)(fb - (float)hb);
      }
      if (hf == 0) { aH0[qt] = H; aL0[qt] = L; }
      else         { aH1[qt] = H; aL1[qt] = L; }
    }
  }

  float best[2][4];
  int bidx[2][4];
#pragma unroll
  for (int qt = 0; qt < 2; ++qt)
#pragma unroll
    for (int r = 0; r < 4; ++r) {
      best[qt][r] = -3.4e38f;
      bidx[qt][r] = 0;
    }

  asm volatile("s_waitcnt vmcnt(0) lgkmcnt(0)" ::: "memory");
  __builtin_amdgcn_s_barrier();
  asm volatile("" ::: "memory");

  for (int g = 0; g < NGROUP; ++g) {
    const int C0 = split * CSPLIT + g * GROUP;
    const _Float16* __restrict__ buf = Bs + (g & 1) * IMGH;

    if (g + 1 < NGROUP) {
      // issue next group's DMA into the other buffer. Safe: the barrier at
      // the end of iteration g-1 guarantees all waves finished reading it.
      const _Float16* gimg = Cxs + (size_t)(split * NGROUP + g + 1) * IMGH;
      _Float16* nbuf = Bs + ((g + 1) & 1) * IMGH;
#pragma unroll
      for (int p = 0; p < 4; ++p) {
        const int off = (t + 256 * p) * 8;
        async_copy16(gimg + off, nbuf + off);
      }
      // oldest-first retire: waits this wave's group-g DMAs, leaves the 4
      // just-issued in flight. No other VMEM ops exist in the loop.
      asm volatile("s_waitcnt vmcnt(4)" ::: "memory");
    } else {
      asm volatile("s_waitcnt vmcnt(0)" ::: "memory");
    }
    __builtin_amdgcn_s_barrier();
    asm volatile("" ::: "memory");

    const half8* __restrict__ Bs8 = (const half8*)buf;
    const float* __restrict__ nhg = nh + g * GROUP;
    __builtin_amdgcn_s_setprio(1);
#pragma unroll
    for (int tt = 0; tt < NTILE; ++tt) {
      const int base = tt * 4 * 64 + quad * 16;
      const half8 b0 = Bs8[base + (n16 ^ quad)];              // Ch k[0,32)
      const half8 b1 = Bs8[base + 64 + (n16 ^ (4 + quad))];   // Ch k[32,64)
      const half8 b2 = Bs8[base + 128 + (n16 ^ quad)];        // Cl k[0,32)
      const half8 b3 = Bs8[base + 192 + (n16 ^ (4 + quad))];  // Cl k[32,64)
      const int c = C0 + tt * 16 + n16;
      const float nc = nhg[tt * 16 + n16];
#pragma unroll
      for (int qt = 0; qt < 2; ++qt) {
        f32x4 acc = {nc, nc, nc, nc};
        acc = __builtin_amdgcn_mfma_f32_16x16x32_f16(aH0[qt], b0, acc, 0, 0, 0);
        acc = __builtin_amdgcn_mfma_f32_16x16x32_f16(aH1[qt], b1, acc, 0, 0, 0);
        acc = __builtin_amdgcn_mfma_f32_16x16x32_f16(aH0[qt], b2, acc, 0, 0, 0);
        acc = __builtin_amdgcn_mfma_f32_16x16x32_f16(aH1[qt], b3, acc, 0, 0, 0);
        acc = __builtin_amdgcn_mfma_f32_16x16x32_f16(aL0[qt], b0, acc, 0, 0, 0);
        acc = __builtin_amdgcn_mfma_f32_16x16x32_f16(aL1[qt], b1, acc, 0, 0, 0);
#pragma unroll
        for (int r = 0; r < 4; ++r) {
          const float u = acc[r];
          if (u > best[qt][r]) { best[qt][r] = u; bidx[qt][r] = c; }
        }
      }
    }
    __builtin_amdgcn_s_setprio(0);
    asm volatile("" ::: "memory");
    __builtin_amdgcn_s_barrier();  // all waves done reading buf before the
                                   // DMA two iterations on re-targets it
  }
#pragma unroll
  for (int qt = 0; qt < 2; ++qt)
#pragma unroll
    for (int r = 0; r < 4; ++r) {
      float u = best[qt][r];
      int c = bidx[qt][r];
#pragma unroll
      for (int off = 1; off < 16; off <<= 1) {
        const float u2 = __shfl_xor(u, off, 64);
        const int c2 = __shfl_xor(c, off, 64);
        if (u2 > u || (u2 == u && c2 < c)) { u = u2; c = c2; }
      }
      if (n16 == 0) {
        const int q = Qw + qt * 16 + quad * 4 + r;
        pmax[(size_t)split * NQ + q] = u;
        pidx[(size_t)split * NQ + q] = c;
      }
    }
}

// q-partitioned: merge partial argmax, gather z_q, write idx, loss partial
// (non-atomic, one float per block).
__global__ __launch_bounds__(256) void k_assign(
    const float* __restrict__ z, const float* __restrict__ cb,
    const float* __restrict__ pmax, const int* __restrict__ pidx,
    float* __restrict__ out_zq, float* __restrict__ out_idx,
    int* __restrict__ idx_i, float* __restrict__ parts) {
  const int t = threadIdx.x;
  const int d = t & 63;
  const int w = t >> 6;
  const int q = blockIdx.x * 4 + w;

  const int s = d & 7;
  float v = pmax[(size_t)s * NQ + q];
  int i = pidx[(size_t)s * NQ + q];
#pragma unroll
  for (int off = 1; off < 8; off <<= 1) {
    const float v2 = __shfl_xor(v, off, 64);
    const int i2 = __shfl_xor(i, off, 64);
    if (v2 > v || (v2 == v && i2 < i)) { v = v2; i = i2; }
  }
  const int k = i;  // all lanes agree

  const float zv = z[(size_t)q * DD + d];
  const float cv = cb[(size_t)k * DD + d];
  out_zq[(size_t)q * DD + d] = cv;  // z + (z_q - z)
  const float diff = zv - cv;
  float sq = diff * diff;
#pragma unroll
  for (int off = 1; off < 64; off <<= 1) sq += __shfl_xor(sq, off, 64);
  __shared__ float ss[4];
  if (d == 0) {
    out_idx[q] = (float)k;  // exact in f32 (k < 8192)
    idx_i[q] = k;
    ss[w] = sq;
  }
  __syncthreads();
  if (t == 0) parts[blockIdx.x] = ss[0] + ss[1] + ss[2] + ss[3];
}

// k-partitioned tail: gather dw/cs for 32 owned codes into LDS (ballot scan
// of idx stream), then compute new_cs/new_codebook/new_ws directly. Block 0
// also reduces the loss partials. Zero global atomics anywhere.
__global__ __launch_bounds__(256) void k_tail(
    const float* __restrict__ z, const int* __restrict__ idx_i,
    const float* __restrict__ ema_cs, const float* __restrict__ ema_ws,
    const float* __restrict__ epart, const float* __restrict__ parts,
    float* __restrict__ out_ncs, float* __restrict__ out_ncb,
    float* __restrict__ out_nws, float* __restrict__ out_loss) {
  __shared__ float acc[SC_CODES * 64];  // 8 KB
  __shared__ int cnt[SC_CODES];
  const int t = threadIdx.x;
  const int k0 = blockIdx.x * SC_CODES;
  for (int i = t; i < SC_CODES * 64; i += 256) acc[i] = 0.f;
  if (t < SC_CODES) cnt[t] = 0;
  __syncthreads();

  const int w = t >> 6, lane = t & 63;
  const int qbase = w * (NQ / 4);
#pragma unroll 4
  for (int it = 0; it < NQ / 4 / 64; ++it) {  // 64 iterations
    const int q = qbase + it * 64 + lane;
    const int kv = idx_i[q];
    const bool hit = (unsigned)(kv - k0) < (unsigned)SC_CODES;
    unsigned long long m = __ballot(hit);
    while (m) {
      const int j = __ffsll(m) - 1;
      m &= m - 1;
      const int kj = __shfl(kv, j, 64);
      const int qj = qbase + it * 64 + j;
      const float zvj = z[(size_t)qj * DD + lane];
      atomicAdd(&acc[(kj - k0) * 64 + lane], zvj);
      if (lane == 0) atomicAdd(&cnt[kj - k0], 1);
    }
  }
  __syncthreads();

  // n = 0.99*sum(ema_cs) + 0.01*NQ  (sum(counts) == NQ exactly)
  float esum = 0.f;
#pragma unroll
  for (int b = 0; b < 32; ++b) esum += epart[b];
  const float n = 0.99f * esum + 0.01f * 16384.0f;

  for (int i = t; i < SC_CODES * 64; i += 256) {
    const int kl = i >> 6;
    const int k = k0 + kl;
    const float v = 0.99f * ema_cs[k] + 0.01f * (float)cnt[kl];
    const float smoothed = (v + 1e-5f) / (n + (float)KC * 1e-5f) * n;
    const float nws = 0.99f * ema_ws[(size_t)k * DD + (i & 63)] + 0.01f * acc[i];
    out_nws[(size_t)k0 * DD + i] = nws;
    out_ncb[(size_t)k0 * DD + i] = nws / smoothed;
  }
  if (t < SC_CODES)
    out_ncs[k0 + t] = 0.99f * ema_cs[k0 + t] + 0.01f * (float)cnt[t];

  if (blockIdx.x == 0) {
    __syncthreads();  // acc no longer needed; reuse as reduce scratch
    float s = 0.f;
    for (int i = t; i < 4096; i += 256) s += parts[i];
#pragma unroll
    for (int off = 1; off < 64; off <<= 1) s += __shfl_xor(s, off, 64);
    if ((t & 63) == 0) acc[t >> 6] = s;
    __syncthreads();
    if (t == 0)
      *out_loss = 1.25f * (acc[0] + acc[1] + acc[2] + acc[3]) *
                  (1.0f / 1048576.0f);
  }
}

extern "C" void kernel_launch(void* const* d_in, const int* in_sizes, int n_in,
                              void* d_out, int out_size, void* d_ws,
                              size_t ws_size, hipStream_t stream) {
  const float* z = (const float*)d_in[0];
  const float* cb = (const float*)d_in[1];
  const float* ema_cs = (const float*)d_in[2];
  const float* ema_ws = (const float*)d_in[3];

  float* out = (float*)d_out;
  float* zq_out = out;              // 1048576
  float* loss_out = out + 1048576;  // 1
  float* idx_out = out + 1048577;   // 16384
  float* ncb_out = out + 1064961;   // 524288
  float* ncs_out = out + 1589249;   // 8192
  float* nws_out = out + 1597441;   // 524288

  float* ws = (float*)d_ws;
  float* nhcn = ws;                        // 8192
  float* epart = ws + 8192;                // 32
  float* parts = ws + 8256;                // 4096
  float* pmax = ws + 12352;                // 131072
  int* pidx = (int*)(ws + 143424);         // 131072
  int* idx_i = (int*)(ws + 274496);        // 16384
  _Float16* Cxs = (_Float16*)(ws + 290880);  // 1048576 halves (2 MB)

  k_prep<<<KC * 16 / 256, 256, 0, stream>>>(cb, ema_cs, Cxs, nhcn, epart);
  k_mfma<<<dim3(NQ / 128, NSPLIT), 256, 0, stream>>>(z, Cxs, nhcn, pmax, pidx);
  k_assign<<<NQ / 4, 256, 0, stream>>>(z, cb, pmax, pidx, zq_out, idx_out,
                                       idx_i, parts);
  k_tail<<<SC_BLOCKS, 256, 0, stream>>>(z, idx_i, ema_cs, ema_ws, epart, parts,
                                        ncs_out, ncb_out, nws_out, loss_out);
}